// Round 1
// baseline (338.875 us; speedup 1.0000x reference)
//
#include <hip/hip_runtime.h>
#include <hip/hip_bf16.h>
#include <stdint.h>

// ---------- common types/helpers ----------
typedef unsigned short u16;
typedef __attribute__((ext_vector_type(8))) short s16x8;   // 8 bf16 (4 VGPRs) MFMA operand
typedef __attribute__((ext_vector_type(4))) float f32x4;   // MFMA accumulator

__device__ __forceinline__ u16 f2bf(float f){              // RNE f32->bf16
  uint32_t u = __builtin_bit_cast(uint32_t, f);
  u += 0x7FFFu + ((u >> 16) & 1u);
  return (u16)(u >> 16);
}
__device__ __forceinline__ float bf2f(u16 h){
  uint32_t u = ((uint32_t)h) << 16;
  return __builtin_bit_cast(float, u);
}
// async global->LDS, 16B per lane. LDS dest is wave-uniform base (+lane*16 by HW).
__device__ __forceinline__ void gl_lds16(const void* g, void* l){
  __builtin_amdgcn_global_load_lds((__attribute__((address_space(1))) void*)g,
                                   (__attribute__((address_space(3))) void*)l,
                                   16, 0, 0);
}

// Problem constants
#define MROWS 16384      // B*L
#define DMODEL 1024
#define NQKV 3072
#define NSEGS 64         // B * (L/SEG)
// ws offsets (bytes)
#define O_XB    0u
#define O_WQKV  33554432u
#define O_WO    39845888u
#define O_BQKV  41943040u
#define O_QKV   41955328u
#define O_VT    142618624u
#define O_GOUT  176173056u

// ---------- kernel 1: pack f32 -> bf16 (x, Wq|Wk|Wv, Wo) + bias concat ----------
__global__ __launch_bounds__(256) void pack_kernel(
    const float* __restrict__ x,
    const float* __restrict__ wq, const float* __restrict__ wk,
    const float* __restrict__ wv, const float* __restrict__ wo,
    const float* __restrict__ bq, const float* __restrict__ bk, const float* __restrict__ bv,
    u16* __restrict__ xb, u16* __restrict__ wqkvb, u16* __restrict__ wob,
    float* __restrict__ bqkv)
{
  const int stride = gridDim.x * 256;
  const int gid = blockIdx.x * 256 + threadIdx.x;
  if(gid < 3072)
    bqkv[gid] = (gid < 1024) ? bq[gid] : (gid < 2048 ? bk[gid - 1024] : bv[gid - 2048]);
  for(int q = gid; q < 4194304; q += stride){          // x: 16.7M elems
    float4 v = *(const float4*)(x + (size_t)q * 4);
    ushort4 o; o.x = f2bf(v.x); o.y = f2bf(v.y); o.z = f2bf(v.z); o.w = f2bf(v.w);
    *(ushort4*)(xb + (size_t)q * 4) = o;
  }
  for(int q = gid; q < 786432; q += stride){           // Wqkv: 3M elems
    int elem = q << 2;
    int m = elem >> 20;                                // 0=Wq 1=Wk 2=Wv (1024 rows each)
    const float* s = (m == 0) ? wq : (m == 1 ? wk : wv);
    float4 v = *(const float4*)(s + (elem & 1048575));
    ushort4 o; o.x = f2bf(v.x); o.y = f2bf(v.y); o.z = f2bf(v.z); o.w = f2bf(v.w);
    *(ushort4*)(wqkvb + elem) = o;
  }
  for(int q = gid; q < 262144; q += stride){           // Wo: 1M elems
    float4 v = *(const float4*)(wo + (size_t)q * 4);
    ushort4 o; o.x = f2bf(v.x); o.y = f2bf(v.y); o.z = f2bf(v.z); o.w = f2bf(v.w);
    *(ushort4*)(wob + (size_t)q * 4) = o;
  }
}

// ---------- kernel 2/6: bf16 GEMM  C[M][ldc] = A[M][K] @ Bt[N][K]^T + bias ----------
// m97 structure: 128x128 tile, BK=64, 4 waves (2x2), global_load_lds(16B),
// XOR-swizzled LDS (inverse-swizzled global source + swizzled ds_read, rule #21).
template<bool OUT_BF16>
__global__ __launch_bounds__(256) void gemm_bt_kernel(
    const u16* __restrict__ A, const u16* __restrict__ Bt,
    const float* __restrict__ bias, void* __restrict__ Cv,
    const int K, const int ldc)
{
  __shared__ char sm[32768];
  char* As = sm;            // 128 rows x 64 bf16 (128B rows)
  char* Bs = sm + 16384;
  const int tid = threadIdx.x;
  const int wv = tid >> 6, lane = tid & 63;
  const int l15 = lane & 15, l4 = lane >> 4;
  const int brow = blockIdx.y << 7, bcol = blockIdx.x << 7;
  const int wr = (wv >> 1) << 6, wc = (wv & 1) << 6;

  const f32x4 fz = {0.f, 0.f, 0.f, 0.f};
  f32x4 acc[4][4];
#pragma unroll
  for(int m = 0; m < 4; ++m)
#pragma unroll
    for(int n = 0; n < 4; ++n) acc[m][n] = fz;

  const int nK = K >> 6;
  for(int kt = 0; kt < nK; ++kt){
    const int k0 = kt << 6;
#pragma unroll
    for(int r = 0; r < 4; ++r){
      uint32_t off = (uint32_t)(r * 4096 + wv * 1024 + lane * 16); // linear LDS byte
      uint32_t row = off >> 7;
      uint32_t ke  = ((off & 127u) ^ ((row & 7u) << 4)) >> 1;      // inverse swizzle on src
      gl_lds16(A  + (size_t)(brow + row) * K + (k0 + ke), As + r * 4096 + wv * 1024);
      gl_lds16(Bt + (size_t)(bcol + row) * K + (k0 + ke), Bs + r * 4096 + wv * 1024);
    }
    __syncthreads();
#pragma unroll
    for(int kk = 0; kk < 64; kk += 32){
      const uint32_t kb = (uint32_t)((kk + (l4 << 3)) << 1);
      s16x8 a[4], b[4];
#pragma unroll
      for(int m = 0; m < 4; ++m){
        uint32_t rw = (uint32_t)(wr + m * 16 + l15);
        a[m] = *(const s16x8*)(As + (rw << 7) + (kb ^ ((rw & 7u) << 4)));
      }
#pragma unroll
      for(int n = 0; n < 4; ++n){
        uint32_t rw = (uint32_t)(wc + n * 16 + l15);
        b[n] = *(const s16x8*)(Bs + (rw << 7) + (kb ^ ((rw & 7u) << 4)));
      }
#pragma unroll
      for(int m = 0; m < 4; ++m)
#pragma unroll
        for(int n = 0; n < 4; ++n)
          acc[m][n] = __builtin_amdgcn_mfma_f32_16x16x32_bf16(a[m], b[n], acc[m][n], 0, 0, 0);
    }
    __syncthreads();
  }

  float bvv[4];
#pragma unroll
  for(int n = 0; n < 4; ++n) bvv[n] = bias[bcol + wc + n * 16 + l15];
#pragma unroll
  for(int m = 0; m < 4; ++m)
#pragma unroll
    for(int n = 0; n < 4; ++n)
#pragma unroll
      for(int r = 0; r < 4; ++r){
        const int row = brow + wr + m * 16 + (l4 << 2) + r;
        const int col = bcol + wc + n * 16 + l15;
        const float v = acc[m][n][r] + bvv[n];
        if constexpr(OUT_BF16) ((u16*)Cv)[(size_t)row * ldc + col] = f2bf(v);
        else                   ((float*)Cv)[(size_t)row * ldc + col] = v;
      }
}

// ---------- kernel 3: per-segment V transpose (256x1024 -> 1024x256) ----------
__global__ __launch_bounds__(256) void transpose_v_kernel(
    const u16* __restrict__ QKV, u16* __restrict__ Vt)
{
  __shared__ u16 tile[64 * 65];
  const int bid = blockIdx.x;
  const int seg = bid >> 6, t = bid & 63;
  const int t0 = (t >> 4) << 6;     // 4 tiles over t (256)
  const int e0 = (t & 15) << 6;     // 16 tiles over e (1024)
  const int tid = threadIdx.x;
#pragma unroll
  for(int i = 0; i < 16; ++i){
    int idx = i * 256 + tid; int r = idx >> 6, c = idx & 63;
    tile[r * 65 + c] = QKV[((size_t)seg * 256 + t0 + r) * NQKV + 2048 + e0 + c];
  }
  __syncthreads();
#pragma unroll
  for(int i = 0; i < 16; ++i){
    int idx = i * 256 + tid; int r = idx >> 6, c = idx & 63;
    Vt[((size_t)seg * 1024 + e0 + r) * 256 + t0 + c] = tile[c * 65 + r];
  }
}

// ---------- kernel 4: global attention (tiny; Qg/Kg/Vg are rows s=0 of Q/K/V) ----------
__global__ __launch_bounds__(256) void global_attn_kernel(
    const u16* __restrict__ QKV, float* __restrict__ gout)
{
  const int b = blockIdx.x, tid = threadIdx.x;
  __shared__ float sc[16][17];
  __shared__ float pr[16][17];
  const int i = tid >> 4, j = tid & 15;
  const u16* qi = QKV + (size_t)(b * 16 + i) * 256 * NQKV;
  const u16* kj = QKV + (size_t)(b * 16 + j) * 256 * NQKV + 1024;
  float a = 0.f;
  for(int d = 0; d < 1024; d += 4){
    ushort4 qv = *(const ushort4*)(qi + d);
    ushort4 kv = *(const ushort4*)(kj + d);
    a += bf2f(qv.x) * bf2f(kv.x) + bf2f(qv.y) * bf2f(kv.y)
       + bf2f(qv.z) * bf2f(kv.z) + bf2f(qv.w) * bf2f(kv.w);
  }
  sc[i][j] = a * 0.125f;
  __syncthreads();
  if(tid < 16){
    float m = -1e30f;
    for(int jj = 0; jj < 16; ++jj) m = fmaxf(m, sc[tid][jj]);
    float s = 0.f;
    for(int jj = 0; jj < 16; ++jj){ float p = __expf(sc[tid][jj] - m); pr[tid][jj] = p; s += p; }
    float inv = 1.f / s;
    for(int jj = 0; jj < 16; ++jj) pr[tid][jj] *= inv;
  }
  __syncthreads();
  for(int rep = 0; rep < 4; ++rep){
    int e = rep * 256 + tid;
    float vv[16];
#pragma unroll
    for(int m2 = 0; m2 < 16; ++m2)
      vv[m2] = bf2f(QKV[(size_t)(b * 16 + m2) * 256 * NQKV + 2048 + e]);
    for(int i2 = 0; i2 < 16; ++i2){
      float o = 0.f;
#pragma unroll
      for(int m2 = 0; m2 < 16; ++m2) o += pr[i2][m2] * vv[m2];
      gout[((size_t)b * 16 + i2) * 1024 + e] = o;
    }
  }
}

// ---------- kernel 5: fused local attention ----------
// block = 4 waves, 64 Q rows (seg, rowtile). Wave w owns S rows [w*16,+16) x 256 cols.
// phase1: S = Q@K^T (MFMA, K/Q staged via global_load_lds, swizzled)
// softmax in-register (shfl_xor over the 16 col-lanes), P -> swizzled LDS (bf16)
// phase2: out = P @ V via Vt (Bt-layout), + global_out, write bf16.
__global__ __launch_bounds__(256) void attn_local_kernel(
    const u16* __restrict__ QKV, const u16* __restrict__ Vt,
    const float* __restrict__ gout, u16* __restrict__ AO)
{
  __shared__ char sm[65536];
  char* Qs  = sm;           // phase1: 64x64 bf16 (8KB)
  char* Ks  = sm + 8192;    // phase1: 256x64 bf16 (32KB)
  char* Ps  = sm;           // phase2: 64x256 bf16 (32KB) — overwrites Qs/Ks after phase1
  char* Vts = sm + 32768;   // phase2: 256x64 bf16 (32KB)
  const int tid = threadIdx.x;
  const int wv = tid >> 6, lane = tid & 63;
  const int l15 = lane & 15, l4 = lane >> 4;
  const int seg = blockIdx.x >> 2, rt = blockIdx.x & 3;
  const int r0 = rt << 6;
  const size_t segQ = (size_t)seg * 256 * NQKV;

  const f32x4 fz = {0.f, 0.f, 0.f, 0.f};
  f32x4 acc[16];
#pragma unroll
  for(int n = 0; n < 16; ++n) acc[n] = fz;

  // ---- phase 1: S(64x256) over K=1024 ----
  for(int dt = 0; dt < 16; ++dt){
    const int d0 = dt << 6;
#pragma unroll
    for(int r = 0; r < 2; ++r){  // Qs 8KB
      uint32_t off = (uint32_t)(r * 4096 + wv * 1024 + lane * 16);
      uint32_t row = off >> 7;
      uint32_t ke  = ((off & 127u) ^ ((row & 7u) << 4)) >> 1;
      gl_lds16(QKV + segQ + (size_t)(r0 + row) * NQKV + (d0 + ke), Qs + r * 4096 + wv * 1024);
    }
#pragma unroll
    for(int r = 0; r < 8; ++r){  // Ks 32KB
      uint32_t off = (uint32_t)(r * 4096 + wv * 1024 + lane * 16);
      uint32_t row = off >> 7;
      uint32_t ke  = ((off & 127u) ^ ((row & 7u) << 4)) >> 1;
      gl_lds16(QKV + segQ + (size_t)row * NQKV + (1024 + d0 + ke), Ks + r * 4096 + wv * 1024);
    }
    __syncthreads();
#pragma unroll
    for(int kk = 0; kk < 64; kk += 32){
      const uint32_t kb = (uint32_t)((kk + (l4 << 3)) << 1);
      const uint32_t qrow = (uint32_t)(wv * 16 + l15);
      s16x8 a = *(const s16x8*)(Qs + (qrow << 7) + (kb ^ ((qrow & 7u) << 4)));
#pragma unroll
      for(int n = 0; n < 16; ++n){
        const uint32_t krow = (uint32_t)(n * 16 + l15);
        s16x8 b = *(const s16x8*)(Ks + (krow << 7) + (kb ^ ((krow & 7u) << 4)));
        acc[n] = __builtin_amdgcn_mfma_f32_16x16x32_bf16(a, b, acc[n], 0, 0, 0);
      }
    }
    __syncthreads();
  }

  // ---- softmax (rows are lane-group-local: reg r -> row (l>>4)*4+r; 16 col-lanes) ----
  const float CE = 0.18033688011112042f;  // SCALE * log2(e)
  float mx[4] = {-1e30f, -1e30f, -1e30f, -1e30f};
#pragma unroll
  for(int n = 0; n < 16; ++n)
#pragma unroll
    for(int r = 0; r < 4; ++r) mx[r] = fmaxf(mx[r], acc[n][r]);
#pragma unroll
  for(int off = 8; off >= 1; off >>= 1)
#pragma unroll
    for(int r = 0; r < 4; ++r) mx[r] = fmaxf(mx[r], __shfl_xor(mx[r], off, 64));
  float sum[4] = {0.f, 0.f, 0.f, 0.f};
#pragma unroll
  for(int n = 0; n < 16; ++n)
#pragma unroll
    for(int r = 0; r < 4; ++r){
      float p = exp2f((acc[n][r] - mx[r]) * CE);
      acc[n][r] = p;
      sum[r] += p;
    }
#pragma unroll
  for(int off = 8; off >= 1; off >>= 1)
#pragma unroll
    for(int r = 0; r < 4; ++r) sum[r] += __shfl_xor(sum[r], off, 64);
  float inv[4];
#pragma unroll
  for(int r = 0; r < 4; ++r) inv[r] = 1.f / sum[r];
  // P -> LDS bf16, 512B rows, swizzled
#pragma unroll
  for(int n = 0; n < 16; ++n)
#pragma unroll
    for(int r = 0; r < 4; ++r){
      uint32_t prow = (uint32_t)(wv * 16 + (l4 << 2) + r);
      uint32_t pcol = (uint32_t)(n * 16 + l15);
      *(u16*)(Ps + (prow << 9) + ((pcol << 1) ^ ((prow & 7u) << 4))) = f2bf(acc[n][r] * inv[r]);
    }

  // ---- phase 2: out(64x1024) = P(64x256) @ V(256x1024); wave w -> cols [w*256,+256) ----
  const size_t vtb = (size_t)seg * 1024 * 256;
  for(int ns = 0; ns < 4; ++ns){
    f32x4 oc[4][4];
#pragma unroll
    for(int m = 0; m < 4; ++m)
#pragma unroll
      for(int n = 0; n < 4; ++n) oc[m][n] = fz;
    for(int ts = 0; ts < 4; ++ts){
      __syncthreads();                       // prior Vts reads / P writes done
      const int t0 = ts << 6;
#pragma unroll
      for(int r = 0; r < 8; ++r){            // Vts 32KB: 256 e-rows x 64 t
        uint32_t off = (uint32_t)(r * 4096 + wv * 1024 + lane * 16);
        uint32_t row = off >> 7;
        uint32_t ke  = ((off & 127u) ^ ((row & 7u) << 4)) >> 1;
        uint32_t eg  = (row >> 6) * 256 + (uint32_t)ns * 64 + (row & 63u);
        gl_lds16(Vt + vtb + (size_t)eg * 256 + (t0 + ke), Vts + r * 4096 + wv * 1024);
      }
      __syncthreads();                       // staging visible
#pragma unroll
      for(int kk = 0; kk < 64; kk += 32){
        const uint32_t kb = (uint32_t)((kk + (l4 << 3)) << 1);
        s16x8 a[4], b[4];
#pragma unroll
        for(int m = 0; m < 4; ++m){
          uint32_t prow = (uint32_t)(m * 16 + l15);
          uint32_t pk   = (uint32_t)((t0 + kk + (l4 << 3)) << 1);
          a[m] = *(const s16x8*)(Ps + (prow << 9) + (pk ^ ((prow & 7u) << 4)));
        }
#pragma unroll
        for(int n = 0; n < 4; ++n){
          uint32_t vrow = (uint32_t)(wv * 64 + n * 16 + l15);
          b[n] = *(const s16x8*)(Vts + (vrow << 7) + (kb ^ ((vrow & 7u) << 4)));
        }
#pragma unroll
        for(int m = 0; m < 4; ++m)
#pragma unroll
          for(int n = 0; n < 4; ++n)
            oc[m][n] = __builtin_amdgcn_mfma_f32_16x16x32_bf16(a[m], b[n], oc[m][n], 0, 0, 0);
      }
    }
    // epilogue for this col chunk: add global attention, write bf16
#pragma unroll
    for(int n = 0; n < 4; ++n){
      const int e = wv * 256 + ns * 64 + n * 16 + l15;
      const float gv = gout[(size_t)seg * 1024 + e];
#pragma unroll
      for(int m = 0; m < 4; ++m)
#pragma unroll
        for(int r = 0; r < 4; ++r){
          const int row = r0 + m * 16 + (l4 << 2) + r;
          AO[((size_t)seg * 256 + row) * 1024 + e] = f2bf(oc[m][n][r] + gv);
        }
    }
  }
}

// ---------- launch ----------
extern "C" void kernel_launch(void* const* d_in, const int* in_sizes, int n_in,
                              void* d_out, int out_size, void* d_ws, size_t ws_size,
                              hipStream_t stream)
{
  const float* x  = (const float*)d_in[0];
  const float* Wq = (const float*)d_in[1];
  const float* bq = (const float*)d_in[2];
  const float* Wk = (const float*)d_in[3];
  const float* bk = (const float*)d_in[4];
  const float* Wv = (const float*)d_in[5];
  const float* bv = (const float*)d_in[6];
  const float* Wo = (const float*)d_in[7];
  const float* bo = (const float*)d_in[8];

  char* ws = (char*)d_ws;
  u16*   xb    = (u16*)(ws + O_XB);
  u16*   wqkvb = (u16*)(ws + O_WQKV);
  u16*   wob   = (u16*)(ws + O_WO);
  float* bqkv  = (float*)(ws + O_BQKV);
  u16*   qkv   = (u16*)(ws + O_QKV);
  u16*   vt    = (u16*)(ws + O_VT);
  float* gout  = (float*)(ws + O_GOUT);
  u16*   ao    = xb;   // alias: xb dead after QKV GEMM

  pack_kernel<<<4096, 256, 0, stream>>>(x, Wq, Wk, Wv, Wo, bq, bk, bv, xb, wqkvb, wob, bqkv);
  gemm_bt_kernel<true><<<dim3(NQKV / 128, MROWS / 128), 256, 0, stream>>>(
      xb, wqkvb, bqkv, qkv, DMODEL, NQKV);
  transpose_v_kernel<<<NSEGS * 64, 256, 0, stream>>>(qkv, vt);
  global_attn_kernel<<<4, 256, 0, stream>>>(qkv, gout);
  attn_local_kernel<<<NSEGS * 4, 256, 0, stream>>>(qkv, vt, gout, ao);
  gemm_bt_kernel<false><<<dim3(DMODEL / 128, MROWS / 128), 256, 0, stream>>>(
      ao, wob, bo, d_out, DMODEL, DMODEL);
}

// Round 2
// 294.907 us; speedup vs baseline: 1.1491x; 1.1491x over previous
//
#include <hip/hip_runtime.h>
#include <hip/hip_bf16.h>
#include <stdint.h>

// ---------- common types/helpers ----------
typedef unsigned short u16;
typedef __attribute__((ext_vector_type(8))) short s16x8;   // 8 bf16 (4 VGPRs) MFMA operand
typedef __attribute__((ext_vector_type(4))) float f32x4;   // MFMA accumulator

__device__ __forceinline__ u16 f2bf(float f){              // RNE f32->bf16
  uint32_t u = __builtin_bit_cast(uint32_t, f);
  u += 0x7FFFu + ((u >> 16) & 1u);
  return (u16)(u >> 16);
}
__device__ __forceinline__ float bf2f(u16 h){
  uint32_t u = ((uint32_t)h) << 16;
  return __builtin_bit_cast(float, u);
}
// async global->LDS, 16B per lane. LDS dest is wave-uniform base (+lane*16 by HW).
__device__ __forceinline__ void gl_lds16(const void* g, void* l){
  __builtin_amdgcn_global_load_lds((__attribute__((address_space(1))) void*)g,
                                   (__attribute__((address_space(3))) void*)l,
                                   16, 0, 0);
}

// Problem constants
#define MROWS 16384      // B*L
#define DMODEL 1024
#define NQKV 3072
#define NSEGS 64         // B * (L/SEG)
// ws offsets (bytes)
#define O_XB    0u
#define O_WQKV  33554432u
#define O_WO    39845888u
#define O_BQKV  41943040u
#define O_QKV   41955328u
#define O_VT    142618624u
#define O_GOUT  176173056u

// ---------- kernel 1: pack f32 -> bf16 (x, Wq|Wk|Wv, Wo) + bias concat ----------
__global__ __launch_bounds__(256) void pack_kernel(
    const float* __restrict__ x,
    const float* __restrict__ wq, const float* __restrict__ wk,
    const float* __restrict__ wv, const float* __restrict__ wo,
    const float* __restrict__ bq, const float* __restrict__ bk, const float* __restrict__ bv,
    u16* __restrict__ xb, u16* __restrict__ wqkvb, u16* __restrict__ wob,
    float* __restrict__ bqkv)
{
  const int stride = gridDim.x * 256;
  const int gid = blockIdx.x * 256 + threadIdx.x;
  if(gid < 3072)
    bqkv[gid] = (gid < 1024) ? bq[gid] : (gid < 2048 ? bk[gid - 1024] : bv[gid - 2048]);
  for(int q = gid; q < 4194304; q += stride){          // x: 16.7M elems
    float4 v = *(const float4*)(x + (size_t)q * 4);
    ushort4 o; o.x = f2bf(v.x); o.y = f2bf(v.y); o.z = f2bf(v.z); o.w = f2bf(v.w);
    *(ushort4*)(xb + (size_t)q * 4) = o;
  }
  for(int q = gid; q < 786432; q += stride){           // Wqkv: 3M elems
    int elem = q << 2;
    int m = elem >> 20;                                // 0=Wq 1=Wk 2=Wv (1024 rows each)
    const float* s = (m == 0) ? wq : (m == 1 ? wk : wv);
    float4 v = *(const float4*)(s + (elem & 1048575));
    ushort4 o; o.x = f2bf(v.x); o.y = f2bf(v.y); o.z = f2bf(v.z); o.w = f2bf(v.w);
    *(ushort4*)(wqkvb + elem) = o;
  }
  for(int q = gid; q < 262144; q += stride){           // Wo: 1M elems
    float4 v = *(const float4*)(wo + (size_t)q * 4);
    ushort4 o; o.x = f2bf(v.x); o.y = f2bf(v.y); o.z = f2bf(v.z); o.w = f2bf(v.w);
    *(ushort4*)(wob + (size_t)q * 4) = o;
  }
}

// ---------- kernel 2/6: 256x256 pipelined bf16 GEMM  C = A @ Bt^T + bias ----------
// 8 waves (2Mx4N), BK=32, 4 LDS buffers (128 KiB), depth-3 prefetch, counted vmcnt
// (never 0 in steady state), raw s_barrier (no __syncthreads drain), setprio around
// MFMA clusters, XCD-swizzled block mapping (nwg % 8 == 0 for both call sites).
template<bool OUT_BF16>
__global__ __launch_bounds__(512, 2) void gemm256_kernel(
    const u16* __restrict__ A, const u16* __restrict__ Bt,
    const float* __restrict__ bias, void* __restrict__ Cv,
    const int K, const int ldc, const int ncb)
{
  __shared__ char sm[131072];   // buf b at b*32768: A 256x32 bf16 (16KB) + B (16KB)
  const int tid = threadIdx.x;
  const int wv = tid >> 6, lane = tid & 63;
  const int l15 = lane & 15, l4 = lane >> 4;
  const int wr = wv >> 2, wc = wv & 3;

  // XCD-aware bijective swizzle (nwg % 8 == 0): each XCD gets contiguous chunk,
  // sweeping columns fastest -> A-panel reuse in per-XCD L2.
  const int nwg = (int)gridDim.x;
  int bid = (int)blockIdx.x;
  bid = (bid & 7) * (nwg >> 3) + (bid >> 3);
  const int brow = (bid / ncb) << 8, bcol = (bid % ncb) << 8;

  // loop-invariant swizzled ds_read byte offsets (64B rows; granule ^= (row>>1)&3)
  int offA[8], offB[4];
#pragma unroll
  for(int m = 0; m < 8; ++m){
    int row = wr * 128 + m * 16 + l15;
    offA[m] = row * 64 + ((l4 ^ ((row >> 1) & 3)) << 4);
  }
#pragma unroll
  for(int n = 0; n < 4; ++n){
    int row = wc * 64 + n * 16 + l15;
    offB[n] = 16384 + row * 64 + ((l4 ^ ((row >> 1) & 3)) << 4);
  }

  // loop-invariant stage addressing: LDS linear dest, inverse-swizzled global src
  const u16* srcA[2]; const u16* srcB[2]; int dstOff[2];
#pragma unroll
  for(int r = 0; r < 2; ++r){
    int off = r * 8192 + tid * 16;
    int row = off >> 6, g = (off >> 4) & 3;
    int gs = g ^ ((row >> 1) & 3);
    srcA[r] = A  + (size_t)(brow + row) * K + gs * 8;
    srcB[r] = Bt + (size_t)(bcol + row) * K + gs * 8;
    dstOff[r] = r * 8192 + wv * 1024;
  }

#define STAGE256(kt_, buf_) do{                                   \
    char* base_ = sm + (buf_) * 32768;                            \
    const int ko_ = (kt_) << 5;                                   \
    gl_lds16(srcA[0] + ko_, base_ + dstOff[0]);                   \
    gl_lds16(srcA[1] + ko_, base_ + dstOff[1]);                   \
    gl_lds16(srcB[0] + ko_, base_ + 16384 + dstOff[0]);           \
    gl_lds16(srcB[1] + ko_, base_ + 16384 + dstOff[1]);           \
  }while(0)

  const f32x4 fz = {0.f, 0.f, 0.f, 0.f};
  f32x4 acc[8][4];
#pragma unroll
  for(int m = 0; m < 8; ++m)
#pragma unroll
    for(int n = 0; n < 4; ++n) acc[m][n] = fz;

  const int nkt = K >> 5;
  STAGE256(0, 0); STAGE256(1, 1); STAGE256(2, 2);

  for(int kt = 0; kt < nkt; ++kt){
    const int rem = nkt - 1 - kt;
    // tile kt ready when <= (4 loads x tiles-in-flight-after-it) remain outstanding
    if(rem >= 2)      asm volatile("s_waitcnt vmcnt(8)" ::: "memory");
    else if(rem == 1) asm volatile("s_waitcnt vmcnt(4)" ::: "memory");
    else              asm volatile("s_waitcnt vmcnt(0)" ::: "memory");
    __builtin_amdgcn_s_barrier();          // raw barrier: no implicit vmcnt(0) drain
    asm volatile("" ::: "memory");
    if(kt + 3 < nkt) STAGE256(kt + 3, (kt + 3) & 3);

    char* cb = sm + (kt & 3) * 32768;
    s16x8 b[4], a[4];
#pragma unroll
    for(int n = 0; n < 4; ++n) b[n] = *(const s16x8*)(cb + offB[n]);
#pragma unroll
    for(int m = 0; m < 4; ++m) a[m] = *(const s16x8*)(cb + offA[m]);
    __builtin_amdgcn_s_setprio(1);
#pragma unroll
    for(int m = 0; m < 4; ++m)
#pragma unroll
      for(int n = 0; n < 4; ++n)
        acc[m][n] = __builtin_amdgcn_mfma_f32_16x16x32_bf16(a[m], b[n], acc[m][n], 0, 0, 0);
    __builtin_amdgcn_s_setprio(0);
#pragma unroll
    for(int m = 0; m < 4; ++m) a[m] = *(const s16x8*)(cb + offA[m + 4]);
    __builtin_amdgcn_s_setprio(1);
#pragma unroll
    for(int m = 0; m < 4; ++m)
#pragma unroll
      for(int n = 0; n < 4; ++n)
        acc[m + 4][n] = __builtin_amdgcn_mfma_f32_16x16x32_bf16(a[m], b[n], acc[m + 4][n], 0, 0, 0);
    __builtin_amdgcn_s_setprio(0);
  }
#undef STAGE256

  float bvv[4];
#pragma unroll
  for(int n = 0; n < 4; ++n) bvv[n] = bias[bcol + wc * 64 + n * 16 + l15];
#pragma unroll
  for(int m = 0; m < 8; ++m)
#pragma unroll
    for(int n = 0; n < 4; ++n)
#pragma unroll
      for(int r = 0; r < 4; ++r){
        const int row = brow + wr * 128 + m * 16 + (l4 << 2) + r;
        const int col = bcol + wc * 64 + n * 16 + l15;
        const float v = acc[m][n][r] + bvv[n];
        if constexpr(OUT_BF16) ((u16*)Cv)[(size_t)row * ldc + col] = f2bf(v);
        else                   ((float*)Cv)[(size_t)row * ldc + col] = v;
      }
}

// ---------- kernel 3: per-segment V transpose (256x1024 -> 1024x256) ----------
__global__ __launch_bounds__(256) void transpose_v_kernel(
    const u16* __restrict__ QKV, u16* __restrict__ Vt)
{
  __shared__ u16 tile[64 * 65];
  const int bid = blockIdx.x;
  const int seg = bid >> 6, t = bid & 63;
  const int t0 = (t >> 4) << 6;     // 4 tiles over t (256)
  const int e0 = (t & 15) << 6;     // 16 tiles over e (1024)
  const int tid = threadIdx.x;
#pragma unroll
  for(int i = 0; i < 16; ++i){
    int idx = i * 256 + tid; int r = idx >> 6, c = idx & 63;
    tile[r * 65 + c] = QKV[((size_t)seg * 256 + t0 + r) * NQKV + 2048 + e0 + c];
  }
  __syncthreads();
#pragma unroll
  for(int i = 0; i < 16; ++i){
    int idx = i * 256 + tid; int r = idx >> 6, c = idx & 63;
    Vt[((size_t)seg * 1024 + e0 + r) * 256 + t0 + c] = tile[c * 65 + r];
  }
}

// ---------- kernel 4: global attention (tiny; Qg/Kg/Vg are rows s=0 of Q/K/V) ----------
__global__ __launch_bounds__(256) void global_attn_kernel(
    const u16* __restrict__ QKV, float* __restrict__ gout)
{
  const int b = blockIdx.x, tid = threadIdx.x;
  __shared__ float sc[16][17];
  __shared__ float pr[16][17];
  const int i = tid >> 4, j = tid & 15;
  const u16* qi = QKV + (size_t)(b * 16 + i) * 256 * NQKV;
  const u16* kj = QKV + (size_t)(b * 16 + j) * 256 * NQKV + 1024;
  float a = 0.f;
  for(int d = 0; d < 1024; d += 4){
    ushort4 qv = *(const ushort4*)(qi + d);
    ushort4 kv = *(const ushort4*)(kj + d);
    a += bf2f(qv.x) * bf2f(kv.x) + bf2f(qv.y) * bf2f(kv.y)
       + bf2f(qv.z) * bf2f(kv.z) + bf2f(qv.w) * bf2f(kv.w);
  }
  sc[i][j] = a * 0.125f;
  __syncthreads();
  if(tid < 16){
    float m = -1e30f;
    for(int jj = 0; jj < 16; ++jj) m = fmaxf(m, sc[tid][jj]);
    float s = 0.f;
    for(int jj = 0; jj < 16; ++jj){ float p = __expf(sc[tid][jj] - m); pr[tid][jj] = p; s += p; }
    float inv = 1.f / s;
    for(int jj = 0; jj < 16; ++jj) pr[tid][jj] *= inv;
  }
  __syncthreads();
  for(int rep = 0; rep < 4; ++rep){
    int e = rep * 256 + tid;
    float vv[16];
#pragma unroll
    for(int m2 = 0; m2 < 16; ++m2)
      vv[m2] = bf2f(QKV[(size_t)(b * 16 + m2) * 256 * NQKV + 2048 + e]);
    for(int i2 = 0; i2 < 16; ++i2){
      float o = 0.f;
#pragma unroll
      for(int m2 = 0; m2 < 16; ++m2) o += pr[i2][m2] * vv[m2];
      gout[((size_t)b * 16 + i2) * 1024 + e] = o;
    }
  }
}

// ---------- kernel 5: fused local attention ----------
__global__ __launch_bounds__(256) void attn_local_kernel(
    const u16* __restrict__ QKV, const u16* __restrict__ Vt,
    const float* __restrict__ gout, u16* __restrict__ AO)
{
  __shared__ char sm[65536];
  char* Qs  = sm;           // phase1: 64x64 bf16 (8KB)
  char* Ks  = sm + 8192;    // phase1: 256x64 bf16 (32KB)
  char* Ps  = sm;           // phase2: 64x256 bf16 (32KB)
  char* Vts = sm + 32768;   // phase2: 256x64 bf16 (32KB)
  const int tid = threadIdx.x;
  const int wv = tid >> 6, lane = tid & 63;
  const int l15 = lane & 15, l4 = lane >> 4;
  const int seg = blockIdx.x >> 2, rt = blockIdx.x & 3;
  const int r0 = rt << 6;
  const size_t segQ = (size_t)seg * 256 * NQKV;

  const f32x4 fz = {0.f, 0.f, 0.f, 0.f};
  f32x4 acc[16];
#pragma unroll
  for(int n = 0; n < 16; ++n) acc[n] = fz;

  for(int dt = 0; dt < 16; ++dt){
    const int d0 = dt << 6;
#pragma unroll
    for(int r = 0; r < 2; ++r){
      uint32_t off = (uint32_t)(r * 4096 + wv * 1024 + lane * 16);
      uint32_t row = off >> 7;
      uint32_t ke  = ((off & 127u) ^ ((row & 7u) << 4)) >> 1;
      gl_lds16(QKV + segQ + (size_t)(r0 + row) * NQKV + (d0 + ke), Qs + r * 4096 + wv * 1024);
    }
#pragma unroll
    for(int r = 0; r < 8; ++r){
      uint32_t off = (uint32_t)(r * 4096 + wv * 1024 + lane * 16);
      uint32_t row = off >> 7;
      uint32_t ke  = ((off & 127u) ^ ((row & 7u) << 4)) >> 1;
      gl_lds16(QKV + segQ + (size_t)row * NQKV + (1024 + d0 + ke), Ks + r * 4096 + wv * 1024);
    }
    __syncthreads();
#pragma unroll
    for(int kk = 0; kk < 64; kk += 32){
      const uint32_t kb = (uint32_t)((kk + (l4 << 3)) << 1);
      const uint32_t qrow = (uint32_t)(wv * 16 + l15);
      s16x8 a = *(const s16x8*)(Qs + (qrow << 7) + (kb ^ ((qrow & 7u) << 4)));
#pragma unroll
      for(int n = 0; n < 16; ++n){
        const uint32_t krow = (uint32_t)(n * 16 + l15);
        s16x8 b = *(const s16x8*)(Ks + (krow << 7) + (kb ^ ((krow & 7u) << 4)));
        acc[n] = __builtin_amdgcn_mfma_f32_16x16x32_bf16(a, b, acc[n], 0, 0, 0);
      }
    }
    __syncthreads();
  }

  const float CE = 0.18033688011112042f;  // SCALE * log2(e)
  float mx[4] = {-1e30f, -1e30f, -1e30f, -1e30f};
#pragma unroll
  for(int n = 0; n < 16; ++n)
#pragma unroll
    for(int r = 0; r < 4; ++r) mx[r] = fmaxf(mx[r], acc[n][r]);
#pragma unroll
  for(int off = 8; off >= 1; off >>= 1)
#pragma unroll
    for(int r = 0; r < 4; ++r) mx[r] = fmaxf(mx[r], __shfl_xor(mx[r], off, 64));
  float sum[4] = {0.f, 0.f, 0.f, 0.f};
#pragma unroll
  for(int n = 0; n < 16; ++n)
#pragma unroll
    for(int r = 0; r < 4; ++r){
      float p = exp2f((acc[n][r] - mx[r]) * CE);
      acc[n][r] = p;
      sum[r] += p;
    }
#pragma unroll
  for(int off = 8; off >= 1; off >>= 1)
#pragma unroll
    for(int r = 0; r < 4; ++r) sum[r] += __shfl_xor(sum[r], off, 64);
  float inv[4];
#pragma unroll
  for(int r = 0; r < 4; ++r) inv[r] = 1.f / sum[r];
#pragma unroll
  for(int n = 0; n < 16; ++n)
#pragma unroll
    for(int r = 0; r < 4; ++r){
      uint32_t prow = (uint32_t)(wv * 16 + (l4 << 2) + r);
      uint32_t pcol = (uint32_t)(n * 16 + l15);
      *(u16*)(Ps + (prow << 9) + ((pcol << 1) ^ ((prow & 7u) << 4))) = f2bf(acc[n][r] * inv[r]);
    }

  const size_t vtb = (size_t)seg * 1024 * 256;
  for(int ns = 0; ns < 4; ++ns){
    f32x4 oc[4][4];
#pragma unroll
    for(int m = 0; m < 4; ++m)
#pragma unroll
      for(int n = 0; n < 4; ++n) oc[m][n] = fz;
    for(int ts = 0; ts < 4; ++ts){
      __syncthreads();
      const int t0 = ts << 6;
#pragma unroll
      for(int r = 0; r < 8; ++r){
        uint32_t off = (uint32_t)(r * 4096 + wv * 1024 + lane * 16);
        uint32_t row = off >> 7;
        uint32_t ke  = ((off & 127u) ^ ((row & 7u) << 4)) >> 1;
        uint32_t eg  = (row >> 6) * 256 + (uint32_t)ns * 64 + (row & 63u);
        gl_lds16(Vt + vtb + (size_t)eg * 256 + (t0 + ke), Vts + r * 4096 + wv * 1024);
      }
      __syncthreads();
#pragma unroll
      for(int kk = 0; kk < 64; kk += 32){
        const uint32_t kb = (uint32_t)((kk + (l4 << 3)) << 1);
        s16x8 a[4], b[4];
#pragma unroll
        for(int m = 0; m < 4; ++m){
          uint32_t prow = (uint32_t)(m * 16 + l15);
          uint32_t pk   = (uint32_t)((t0 + kk + (l4 << 3)) << 1);
          a[m] = *(const s16x8*)(Ps + (prow << 9) + (pk ^ ((prow & 7u) << 4)));
        }
#pragma unroll
        for(int n = 0; n < 4; ++n){
          uint32_t vrow = (uint32_t)(wv * 64 + n * 16 + l15);
          b[n] = *(const s16x8*)(Vts + (vrow << 7) + (kb ^ ((vrow & 7u) << 4)));
        }
#pragma unroll
        for(int m = 0; m < 4; ++m)
#pragma unroll
          for(int n = 0; n < 4; ++n)
            oc[m][n] = __builtin_amdgcn_mfma_f32_16x16x32_bf16(a[m], b[n], oc[m][n], 0, 0, 0);
      }
    }
#pragma unroll
    for(int n = 0; n < 4; ++n){
      const int e = wv * 256 + ns * 64 + n * 16 + l15;
      const float gv = gout[(size_t)seg * 1024 + e];
#pragma unroll
      for(int m = 0; m < 4; ++m)
#pragma unroll
        for(int r = 0; r < 4; ++r){
          const int row = r0 + m * 16 + (l4 << 2) + r;
          AO[((size_t)seg * 256 + row) * 1024 + e] = f2bf(oc[m][n][r] + gv);
        }
    }
  }
}

// ---------- launch ----------
extern "C" void kernel_launch(void* const* d_in, const int* in_sizes, int n_in,
                              void* d_out, int out_size, void* d_ws, size_t ws_size,
                              hipStream_t stream)
{
  const float* x  = (const float*)d_in[0];
  const float* Wq = (const float*)d_in[1];
  const float* bq = (const float*)d_in[2];
  const float* Wk = (const float*)d_in[3];
  const float* bk = (const float*)d_in[4];
  const float* Wv = (const float*)d_in[5];
  const float* bv = (const float*)d_in[6];
  const float* Wo = (const float*)d_in[7];
  const float* bo = (const float*)d_in[8];

  char* ws = (char*)d_ws;
  u16*   xb    = (u16*)(ws + O_XB);
  u16*   wqkvb = (u16*)(ws + O_WQKV);
  u16*   wob   = (u16*)(ws + O_WO);
  float* bqkv  = (float*)(ws + O_BQKV);
  u16*   qkv   = (u16*)(ws + O_QKV);
  u16*   vt    = (u16*)(ws + O_VT);
  float* gout  = (float*)(ws + O_GOUT);
  u16*   ao    = xb;   // alias: xb dead after QKV GEMM

  pack_kernel<<<4096, 256, 0, stream>>>(x, Wq, Wk, Wv, Wo, bq, bk, bv, xb, wqkvb, wob, bqkv);
  gemm256_kernel<true><<<dim3((NQKV / 256) * (MROWS / 256)), 512, 0, stream>>>(
      xb, wqkvb, bqkv, qkv, DMODEL, NQKV, NQKV / 256);
  transpose_v_kernel<<<NSEGS * 64, 256, 0, stream>>>(qkv, vt);
  global_attn_kernel<<<4, 256, 0, stream>>>(qkv, gout);
  attn_local_kernel<<<NSEGS * 4, 256, 0, stream>>>(qkv, vt, gout, ao);
  gemm256_kernel<false><<<dim3((DMODEL / 256) * (MROWS / 256)), 512, 0, stream>>>(
      ao, wob, bo, d_out, DMODEL, DMODEL, DMODEL / 256);
}